// Round 1
// baseline (416.090 us; speedup 1.0000x reference)
//
#include <hip/hip_runtime.h>
#include <hip/hip_bf16.h>
#include <stdint.h>

#define NE 8
#define DK 1024
#define FN 1024
#define NTOK 8192

#define BM 128
#define BN 128
#define BK 64

typedef __attribute__((ext_vector_type(4))) float f32x4;
typedef __attribute__((ext_vector_type(8))) short short8;
typedef __attribute__((ext_vector_type(4))) short short4v;

__device__ __forceinline__ unsigned short f2bf(float f) {
    union { float f; unsigned u; } v; v.f = f;
    unsigned r = v.u;
    unsigned lsb = (r >> 16) & 1u;
    r += 0x7fffu + lsb;
    return (unsigned short)(r >> 16);
}

// ---------------- gating + x -> bf16 conversion (one wave per token) ---------
__global__ __launch_bounds__(256) void k_gate(const float* __restrict__ x,
    const float* __restrict__ Wg, const float* __restrict__ bg,
    unsigned short* __restrict__ xb, int* __restrict__ meta_e,
    float* __restrict__ meta_w, int* __restrict__ counts)
{
    const int lane = threadIdx.x & 63;
    const int t = blockIdx.x * 4 + (threadIdx.x >> 6);

    const f32x4* xr = (const f32x4*)(x + (size_t)t * DK);
    f32x4 xv[4];
#pragma unroll
    for (int c = 0; c < 4; ++c) xv[c] = xr[lane + 64 * c];

    // bf16 convert + store
    short4v* xbo = (short4v*)(xb + (size_t)t * DK);
#pragma unroll
    for (int c = 0; c < 4; ++c) {
        short4v b;
        b.x = (short)f2bf(xv[c].x); b.y = (short)f2bf(xv[c].y);
        b.z = (short)f2bf(xv[c].z); b.w = (short)f2bf(xv[c].w);
        xbo[lane + 64 * c] = b;
    }

    float acc[NE];
#pragma unroll
    for (int e = 0; e < NE; ++e) {
        const f32x4* wr = (const f32x4*)(Wg + e * DK);
        float a = 0.f;
#pragma unroll
        for (int c = 0; c < 4; ++c) {
            f32x4 wv = wr[lane + 64 * c];
            a += xv[c].x * wv.x + xv[c].y * wv.y + xv[c].z * wv.z + xv[c].w * wv.w;
        }
        acc[e] = a;
    }
#pragma unroll
    for (int e = 0; e < NE; ++e) {
        float a = acc[e];
#pragma unroll
        for (int off = 32; off > 0; off >>= 1) a += __shfl_xor(a, off, 64);
        acc[e] = a;
    }
    if (lane == 0) {
        float v[NE];
#pragma unroll
        for (int e = 0; e < NE; ++e) v[e] = acc[e] + bg[e];
        int b0 = 0; float m0 = v[0];
#pragma unroll
        for (int e = 1; e < NE; ++e) if (v[e] > m0) { m0 = v[e]; b0 = e; }
        int b1 = -1; float m1 = -3.4e38f;
#pragma unroll
        for (int e = 0; e < NE; ++e) if (e != b0 && v[e] > m1) { m1 = v[e]; b1 = e; }
        float r = expf(m1 - m0);
        float s = 1.f + r;
        float w0 = 1.f / s;
        float w1 = r / s;
        meta_e[2 * t] = b0; meta_e[2 * t + 1] = b1;
        meta_w[2 * t] = w0; meta_w[2 * t + 1] = w1;
        atomicAdd(&counts[b0], 1);
        atomicAdd(&counts[b1], 1);
    }
}

// ---------------- W -> bf16 ---------------------------------------------------
__global__ __launch_bounds__(256) void k_convw(const float* __restrict__ W,
                                               unsigned short* __restrict__ Wb)
{
    int i = blockIdx.x * 256 + threadIdx.x;
    f32x4 v = ((const f32x4*)W)[i];
    short4v b;
    b.x = (short)f2bf(v.x); b.y = (short)f2bf(v.y);
    b.z = (short)f2bf(v.z); b.w = (short)f2bf(v.w);
    ((short4v*)Wb)[i] = b;
}

// ---------------- prefix sum over 8 experts ----------------------------------
__global__ void k_seg(const int* __restrict__ counts, int* __restrict__ seg,
                      int* __restrict__ cursor)
{
    if (threadIdx.x == 0) {
        int s = 0;
        for (int e = 0; e < NE; ++e) { seg[e] = s; cursor[e] = s; s += counts[e]; }
        seg[NE] = s;
    }
}

// ---------------- scatter (token, weight) into per-expert lists --------------
__global__ __launch_bounds__(256) void k_scatter(const int* __restrict__ meta_e,
    const float* __restrict__ meta_w, int* __restrict__ cursor,
    int* __restrict__ rows, float* __restrict__ rw)
{
    int t = blockIdx.x * 256 + threadIdx.x;
#pragma unroll
    for (int k = 0; k < 2; ++k) {
        int e = meta_e[2 * t + k];
        int p = atomicAdd(&cursor[e], 1);
        rows[p] = t;
        rw[p] = meta_w[2 * t + k];
    }
}

// ---------------- grouped GEMM: out[t,:] += w * (x[t] @ W_e^T + b_e) ---------
__global__ __launch_bounds__(256) void k_gemm(const unsigned short* __restrict__ xb,
    const unsigned short* __restrict__ Wb, const float* __restrict__ be,
    const int* __restrict__ seg, const int* __restrict__ rows,
    const float* __restrict__ rw, float* __restrict__ out)
{
    __shared__ unsigned short Al[BM * BK];
    __shared__ unsigned short Bl[BN * BK];

    const int e = blockIdx.z;
    const int s0 = seg[e];
    const int L = seg[e + 1] - s0;
    const int m0 = blockIdx.y * BM;
    if (m0 >= L) return;
    const int n0 = blockIdx.x * BN;

    const int tid = threadIdx.x;
    const int lane = tid & 63;
    const int wid = tid >> 6;
    const int wm = wid >> 1, wn = wid & 1;

    // staging: per call c, rows c*32 + tid/8, col-block tid%8 (16B units)
    const int arow = tid >> 3;
    const int acb = tid & 7;
    const unsigned short* asrc[4];
    const unsigned short* bsrc[4];
#pragma unroll
    for (int c = 0; c < 4; ++c) {
        int r = c * 32 + arow;
        int cbs = acb ^ (r & 7);            // T2 swizzle via pre-swizzled source
        int idx = m0 + r; if (idx >= L) idx = L - 1;
        asrc[c] = xb + (size_t)rows[s0 + idx] * DK + cbs * 8;
        bsrc[c] = Wb + ((size_t)e * FN + n0 + r) * DK + cbs * 8;
    }

    char* AlB = (char*)Al;
    char* BlB = (char*)Bl;

    f32x4 acc[4][4];
#pragma unroll
    for (int i = 0; i < 4; ++i)
#pragma unroll
        for (int j = 0; j < 4; ++j) acc[i][j] = f32x4{0.f, 0.f, 0.f, 0.f};

    const int frow = lane & 15;
    const int fq = lane >> 4;
    int a_off[4][2], b_off[4][2];
#pragma unroll
    for (int mi = 0; mi < 4; ++mi) {
        int row = wm * 64 + mi * 16 + frow;
#pragma unroll
        for (int kk = 0; kk < 2; ++kk) {
            int cb = (kk * 4 + fq) ^ (row & 7);
            a_off[mi][kk] = row * 128 + cb * 16;
        }
    }
#pragma unroll
    for (int ni = 0; ni < 4; ++ni) {
        int row = wn * 64 + ni * 16 + frow;
#pragma unroll
        for (int kk = 0; kk < 2; ++kk) {
            int cb = (kk * 4 + fq) ^ (row & 7);
            b_off[ni][kk] = row * 128 + cb * 16;
        }
    }

    for (int kt = 0; kt < DK / BK; ++kt) {
#pragma unroll
        for (int c = 0; c < 4; ++c) {
            __builtin_amdgcn_global_load_lds(
                (const __attribute__((address_space(1))) void*)(asrc[c] + kt * BK),
                (__attribute__((address_space(3))) void*)(AlB + c * 4096 + wid * 1024),
                16, 0, 0);
        }
#pragma unroll
        for (int c = 0; c < 4; ++c) {
            __builtin_amdgcn_global_load_lds(
                (const __attribute__((address_space(1))) void*)(bsrc[c] + kt * BK),
                (__attribute__((address_space(3))) void*)(BlB + c * 4096 + wid * 1024),
                16, 0, 0);
        }
        __syncthreads();   // compiler drains vmcnt before s_barrier

#pragma unroll
        for (int kk = 0; kk < 2; ++kk) {
            short8 af[4], bfr[4];
#pragma unroll
            for (int mi = 0; mi < 4; ++mi) af[mi] = *(const short8*)(AlB + a_off[mi][kk]);
#pragma unroll
            for (int ni = 0; ni < 4; ++ni) bfr[ni] = *(const short8*)(BlB + b_off[ni][kk]);
#pragma unroll
            for (int mi = 0; mi < 4; ++mi)
#pragma unroll
                for (int ni = 0; ni < 4; ++ni)
                    acc[mi][ni] = __builtin_amdgcn_mfma_f32_16x16x32_bf16(
                        af[mi], bfr[ni], acc[mi][ni], 0, 0, 0);
        }
        __syncthreads();
    }

    // epilogue: D col = lane&15, row = (lane>>4)*4 + j  (HW-verified layout)
    const int fq4 = fq * 4;
#pragma unroll
    for (int mi = 0; mi < 4; ++mi) {
        int rl = m0 + wm * 64 + mi * 16 + fq4;
#pragma unroll
        for (int j = 0; j < 4; ++j) {
            int idx = rl + j;
            if (idx < L) {
                int t = rows[s0 + idx];
                float w = rw[s0 + idx];
                float* orow = out + (size_t)t * FN + n0 + wn * 64 + frow;
#pragma unroll
                for (int ni = 0; ni < 4; ++ni) {
                    float v = w * (acc[mi][ni][j] + be[e * FN + n0 + wn * 64 + ni * 16 + frow]);
                    atomicAdd(orow + ni * 16, v);
                }
            }
        }
    }
}

extern "C" void kernel_launch(void* const* d_in, const int* in_sizes, int n_in,
                              void* d_out, int out_size, void* d_ws, size_t ws_size,
                              hipStream_t stream)
{
    const float* x   = (const float*)d_in[0];
    const float* We  = (const float*)d_in[1];
    const float* beb = (const float*)d_in[2];
    const float* Wg  = (const float*)d_in[3];
    const float* bg  = (const float*)d_in[4];
    float* out = (float*)d_out;

    char* ws = (char*)d_ws;
    unsigned short* xb = (unsigned short*)ws;                       // 16 MB
    unsigned short* Wb = (unsigned short*)(ws + (size_t)(16 << 20)); // 16 MB
    size_t off = (size_t)(32 << 20);
    int*   counts = (int*)(ws + off);   off += 256;
    int*   seg    = (int*)(ws + off);   off += 256;
    int*   cursor = (int*)(ws + off);   off += 256;
    int*   meta_e = (int*)(ws + off);   off += (size_t)NTOK * 2 * 4;
    float* meta_w = (float*)(ws + off); off += (size_t)NTOK * 2 * 4;
    int*   rowsb  = (int*)(ws + off);   off += (size_t)NTOK * 2 * 4;
    float* rwb    = (float*)(ws + off); off += (size_t)NTOK * 2 * 4;

    hipMemsetAsync(d_out, 0, (size_t)NTOK * FN * 4, stream);
    hipMemsetAsync(counts, 0, 32, stream);

    k_gate<<<NTOK / 4, 256, 0, stream>>>(x, Wg, bg, xb, meta_e, meta_w, counts);
    k_convw<<<(NE * FN * DK / 4) / 256, 256, 0, stream>>>(We, Wb);
    k_seg<<<1, 64, 0, stream>>>(counts, seg, cursor);
    k_scatter<<<NTOK / 256, 256, 0, stream>>>(meta_e, meta_w, cursor, rowsb, rwb);

    dim3 g(FN / BN, 32, NE);
    k_gemm<<<g, 256, 0, stream>>>(xb, Wb, beb, seg, rowsb, rwb, out);
}

// Round 2
// 171.075 us; speedup vs baseline: 2.4322x; 2.4322x over previous
//
#include <hip/hip_runtime.h>
#include <hip/hip_bf16.h>
#include <stdint.h>

#define NE 8
#define DK 1024
#define FN 1024
#define NTOK 8192

#define BM 128
#define BN 128
#define BK 64

#define HB 32            // histogram/scatter blocks
#define EPB (NTOK * 2 / HB)   // entries per block = 512

typedef __attribute__((ext_vector_type(4))) float f32x4;
typedef __attribute__((ext_vector_type(8))) short short8;
typedef __attribute__((ext_vector_type(4))) short short4v;

__device__ __forceinline__ unsigned short f2bf(float f) {
    union { float f; unsigned u; } v; v.f = f;
    unsigned r = v.u;
    unsigned lsb = (r >> 16) & 1u;
    r += 0x7fffu + lsb;
    return (unsigned short)(r >> 16);
}

// ---------------- gating + x -> bf16 conversion (one wave per token) ---------
// NO global atomics here (R1 lesson: 16K same-line atomics = 200us drain).
__global__ __launch_bounds__(256) void k_gate(const float* __restrict__ x,
    const float* __restrict__ Wg, const float* __restrict__ bg,
    unsigned short* __restrict__ xb, int* __restrict__ meta_e,
    float* __restrict__ meta_w)
{
    const int lane = threadIdx.x & 63;
    const int t = blockIdx.x * 4 + (threadIdx.x >> 6);

    const f32x4* xr = (const f32x4*)(x + (size_t)t * DK);
    f32x4 xv[4];
#pragma unroll
    for (int c = 0; c < 4; ++c) xv[c] = xr[lane + 64 * c];

    // bf16 convert + store
    short4v* xbo = (short4v*)(xb + (size_t)t * DK);
#pragma unroll
    for (int c = 0; c < 4; ++c) {
        short4v b;
        b.x = (short)f2bf(xv[c].x); b.y = (short)f2bf(xv[c].y);
        b.z = (short)f2bf(xv[c].z); b.w = (short)f2bf(xv[c].w);
        xbo[lane + 64 * c] = b;
    }

    float acc[NE];
#pragma unroll
    for (int e = 0; e < NE; ++e) {
        const f32x4* wr = (const f32x4*)(Wg + e * DK);
        float a = 0.f;
#pragma unroll
        for (int c = 0; c < 4; ++c) {
            f32x4 wv = wr[lane + 64 * c];
            a += xv[c].x * wv.x + xv[c].y * wv.y + xv[c].z * wv.z + xv[c].w * wv.w;
        }
        acc[e] = a;
    }
#pragma unroll
    for (int e = 0; e < NE; ++e) {
        float a = acc[e];
#pragma unroll
        for (int off = 32; off > 0; off >>= 1) a += __shfl_xor(a, off, 64);
        acc[e] = a;
    }
    if (lane == 0) {
        float v[NE];
#pragma unroll
        for (int e = 0; e < NE; ++e) v[e] = acc[e] + bg[e];
        int b0 = 0; float m0 = v[0];
#pragma unroll
        for (int e = 1; e < NE; ++e) if (v[e] > m0) { m0 = v[e]; b0 = e; }
        int b1 = -1; float m1 = -3.4e38f;
#pragma unroll
        for (int e = 0; e < NE; ++e) if (e != b0 && v[e] > m1) { m1 = v[e]; b1 = e; }
        float r = expf(m1 - m0);
        float s = 1.f + r;
        meta_e[2 * t] = b0; meta_e[2 * t + 1] = b1;
        meta_w[2 * t] = 1.f / s; meta_w[2 * t + 1] = r / s;
    }
}

// ---------------- W -> bf16 ---------------------------------------------------
__global__ __launch_bounds__(256) void k_convw(const float* __restrict__ W,
                                               unsigned short* __restrict__ Wb)
{
    int i = blockIdx.x * 256 + threadIdx.x;
    f32x4 v = ((const f32x4*)W)[i];
    short4v b;
    b.x = (short)f2bf(v.x); b.y = (short)f2bf(v.y);
    b.z = (short)f2bf(v.z); b.w = (short)f2bf(v.w);
    ((short4v*)Wb)[i] = b;
}

// ---------------- per-block histogram (LDS atomics only) ---------------------
__global__ __launch_bounds__(256) void k_hist(const int* __restrict__ meta_e,
                                              int* __restrict__ blockcnt)
{
    __shared__ int lh[NE];
    if (threadIdx.x < NE) lh[threadIdx.x] = 0;
    __syncthreads();
    int base = blockIdx.x * EPB;
#pragma unroll
    for (int k = 0; k < EPB / 256; ++k)
        atomicAdd(&lh[meta_e[base + k * 256 + threadIdx.x]], 1);
    __syncthreads();
    if (threadIdx.x < NE) blockcnt[blockIdx.x * NE + threadIdx.x] = lh[threadIdx.x];
}

// ---------------- scan: expert segs + per-block bases ------------------------
__global__ void k_scan(const int* __restrict__ blockcnt, int* __restrict__ seg,
                       int* __restrict__ base)
{
    __shared__ int pre[HB][NE];
    __shared__ int colsum[NE];
    __shared__ int segstart[NE];
    int tid = threadIdx.x;
    if (tid < NE) {
        int run = 0;
        for (int b = 0; b < HB; ++b) { pre[b][tid] = run; run += blockcnt[b * NE + tid]; }
        colsum[tid] = run;
    }
    __syncthreads();
    if (tid == 0) {
        int s = 0;
        for (int e = 0; e < NE; ++e) { segstart[e] = s; seg[e] = s; s += colsum[e]; }
        seg[NE] = s;
    }
    __syncthreads();
    for (int i = tid; i < HB * NE; i += 64) {
        int b = i / NE, e = i % NE;
        base[i] = segstart[e] + pre[b][e];
    }
}

// ---------------- scatter with LDS ranks + precomputed bases -----------------
__global__ __launch_bounds__(256) void k_scatter(const int* __restrict__ meta_e,
    const float* __restrict__ meta_w, const int* __restrict__ base,
    int* __restrict__ rows, float* __restrict__ rw)
{
    __shared__ int lh[NE];
    __shared__ int bb[NE];
    if (threadIdx.x < NE) {
        lh[threadIdx.x] = 0;
        bb[threadIdx.x] = base[blockIdx.x * NE + threadIdx.x];
    }
    __syncthreads();
    int bs = blockIdx.x * EPB;
#pragma unroll
    for (int k = 0; k < EPB / 256; ++k) {
        int i = bs + k * 256 + threadIdx.x;
        int e = meta_e[i];
        int r = atomicAdd(&lh[e], 1);
        int p = bb[e] + r;
        rows[p] = i >> 1;
        rw[p] = meta_w[i];
    }
}

// ---------------- grouped GEMM: out[t,:] += w * (x[t] @ W_e^T + b_e) ---------
__global__ __launch_bounds__(256) void k_gemm(const unsigned short* __restrict__ xb,
    const unsigned short* __restrict__ Wb, const float* __restrict__ be,
    const int* __restrict__ seg, const int* __restrict__ rows,
    const float* __restrict__ rw, float* __restrict__ out)
{
    __shared__ unsigned short Al[BM * BK];
    __shared__ unsigned short Bl[BN * BK];

    const int e = blockIdx.z;
    const int s0 = seg[e];
    const int L = seg[e + 1] - s0;
    const int m0 = blockIdx.y * BM;
    if (m0 >= L) return;
    const int n0 = blockIdx.x * BN;

    const int tid = threadIdx.x;
    const int lane = tid & 63;
    const int wid = tid >> 6;
    const int wm = wid >> 1, wn = wid & 1;

    const int arow = tid >> 3;
    const int acb = tid & 7;
    const unsigned short* asrc[4];
    const unsigned short* bsrc[4];
#pragma unroll
    for (int c = 0; c < 4; ++c) {
        int r = c * 32 + arow;
        int cbs = acb ^ (r & 7);            // T2 swizzle via pre-swizzled source
        int idx = m0 + r; if (idx >= L) idx = L - 1;
        asrc[c] = xb + (size_t)rows[s0 + idx] * DK + cbs * 8;
        bsrc[c] = Wb + ((size_t)e * FN + n0 + r) * DK + cbs * 8;
    }

    char* AlB = (char*)Al;
    char* BlB = (char*)Bl;

    f32x4 acc[4][4];
#pragma unroll
    for (int i = 0; i < 4; ++i)
#pragma unroll
        for (int j = 0; j < 4; ++j) acc[i][j] = f32x4{0.f, 0.f, 0.f, 0.f};

    const int frow = lane & 15;
    const int fq = lane >> 4;
    int a_off[4][2], b_off[4][2];
#pragma unroll
    for (int mi = 0; mi < 4; ++mi) {
        int row = wm * 64 + mi * 16 + frow;
#pragma unroll
        for (int kk = 0; kk < 2; ++kk) {
            int cb = (kk * 4 + fq) ^ (row & 7);
            a_off[mi][kk] = row * 128 + cb * 16;
        }
    }
#pragma unroll
    for (int ni = 0; ni < 4; ++ni) {
        int row = wn * 64 + ni * 16 + frow;
#pragma unroll
        for (int kk = 0; kk < 2; ++kk) {
            int cb = (kk * 4 + fq) ^ (row & 7);
            b_off[ni][kk] = row * 128 + cb * 16;
        }
    }

    for (int kt = 0; kt < DK / BK; ++kt) {
#pragma unroll
        for (int c = 0; c < 4; ++c) {
            __builtin_amdgcn_global_load_lds(
                (const __attribute__((address_space(1))) void*)(asrc[c] + kt * BK),
                (__attribute__((address_space(3))) void*)(AlB + c * 4096 + wid * 1024),
                16, 0, 0);
        }
#pragma unroll
        for (int c = 0; c < 4; ++c) {
            __builtin_amdgcn_global_load_lds(
                (const __attribute__((address_space(1))) void*)(bsrc[c] + kt * BK),
                (__attribute__((address_space(3))) void*)(BlB + c * 4096 + wid * 1024),
                16, 0, 0);
        }
        __syncthreads();

#pragma unroll
        for (int kk = 0; kk < 2; ++kk) {
            short8 af[4], bfr[4];
#pragma unroll
            for (int mi = 0; mi < 4; ++mi) af[mi] = *(const short8*)(AlB + a_off[mi][kk]);
#pragma unroll
            for (int ni = 0; ni < 4; ++ni) bfr[ni] = *(const short8*)(BlB + b_off[ni][kk]);
#pragma unroll
            for (int mi = 0; mi < 4; ++mi)
#pragma unroll
                for (int ni = 0; ni < 4; ++ni)
                    acc[mi][ni] = __builtin_amdgcn_mfma_f32_16x16x32_bf16(
                        af[mi], bfr[ni], acc[mi][ni], 0, 0, 0);
        }
        __syncthreads();
    }

    const int fq4 = fq * 4;
#pragma unroll
    for (int mi = 0; mi < 4; ++mi) {
        int rl = m0 + wm * 64 + mi * 16 + fq4;
#pragma unroll
        for (int j = 0; j < 4; ++j) {
            int idx = rl + j;
            if (idx < L) {
                int t = rows[s0 + idx];
                float w = rw[s0 + idx];
                float* orow = out + (size_t)t * FN + n0 + wn * 64 + frow;
#pragma unroll
                for (int ni = 0; ni < 4; ++ni) {
                    float v = w * (acc[mi][ni][j] + be[e * FN + n0 + wn * 64 + ni * 16 + frow]);
                    atomicAdd(orow + ni * 16, v);
                }
            }
        }
    }
}

extern "C" void kernel_launch(void* const* d_in, const int* in_sizes, int n_in,
                              void* d_out, int out_size, void* d_ws, size_t ws_size,
                              hipStream_t stream)
{
    const float* x   = (const float*)d_in[0];
    const float* We  = (const float*)d_in[1];
    const float* beb = (const float*)d_in[2];
    const float* Wg  = (const float*)d_in[3];
    const float* bg  = (const float*)d_in[4];
    float* out = (float*)d_out;

    char* ws = (char*)d_ws;
    unsigned short* xb = (unsigned short*)ws;                        // 16 MB
    unsigned short* Wb = (unsigned short*)(ws + (size_t)(16 << 20)); // 16 MB
    size_t off = (size_t)(32 << 20);
    int*   seg      = (int*)(ws + off);   off += 256;
    int*   blockcnt = (int*)(ws + off);   off += HB * NE * 4;
    int*   basebuf  = (int*)(ws + off);   off += HB * NE * 4;
    int*   meta_e   = (int*)(ws + off);   off += (size_t)NTOK * 2 * 4;
    float* meta_w   = (float*)(ws + off); off += (size_t)NTOK * 2 * 4;
    int*   rowsb    = (int*)(ws + off);   off += (size_t)NTOK * 2 * 4;
    float* rwb      = (float*)(ws + off); off += (size_t)NTOK * 2 * 4;

    hipMemsetAsync(d_out, 0, (size_t)NTOK * FN * 4, stream);

    k_gate<<<NTOK / 4, 256, 0, stream>>>(x, Wg, bg, xb, meta_e, meta_w);
    k_convw<<<(NE * FN * DK / 4) / 256, 256, 0, stream>>>(We, Wb);
    k_hist<<<HB, 256, 0, stream>>>(meta_e, blockcnt);
    k_scan<<<1, 64, 0, stream>>>(blockcnt, seg, basebuf);
    k_scatter<<<HB, 256, 0, stream>>>(meta_e, meta_w, basebuf, rowsb, rwb);

    dim3 g(FN / BN, 64, NE);
    k_gemm<<<g, 256, 0, stream>>>(xb, Wb, beb, seg, rowsb, rwb, out);
}

// Round 3
// 133.154 us; speedup vs baseline: 3.1249x; 1.2848x over previous
//
#include <hip/hip_runtime.h>
#include <hip/hip_bf16.h>
#include <stdint.h>

#define NE 8
#define DK 1024
#define FN 1024
#define NTOK 8192

#define BM 128
#define BN 128
#define BK 64
#define NIT (DK / BK)

#define HB 32
#define EPB (NTOK * 2 / HB)

typedef __attribute__((ext_vector_type(4))) float f32x4;
typedef __attribute__((ext_vector_type(8))) short short8;
typedef __attribute__((ext_vector_type(4))) short short4v;

__device__ __forceinline__ unsigned short f2bf(float f) {
    union { float f; unsigned u; } v; v.f = f;
    unsigned r = v.u;
    unsigned lsb = (r >> 16) & 1u;
    r += 0x7fffu + lsb;
    return (unsigned short)(r >> 16);
}
__device__ __forceinline__ float bf2f(unsigned short u) {
    union { unsigned u; float f; } v; v.u = ((unsigned)u) << 16;
    return v.f;
}

// ---------------- gating + x -> bf16 conversion (one wave per token) ---------
__global__ __launch_bounds__(256) void k_gate(const float* __restrict__ x,
    const float* __restrict__ Wg, const float* __restrict__ bg,
    unsigned short* __restrict__ xb, int* __restrict__ meta_e,
    float* __restrict__ meta_w)
{
    const int lane = threadIdx.x & 63;
    const int t = blockIdx.x * 4 + (threadIdx.x >> 6);

    const f32x4* xr = (const f32x4*)(x + (size_t)t * DK);
    f32x4 xv[4];
#pragma unroll
    for (int c = 0; c < 4; ++c) xv[c] = xr[lane + 64 * c];

    short4v* xbo = (short4v*)(xb + (size_t)t * DK);
#pragma unroll
    for (int c = 0; c < 4; ++c) {
        short4v b;
        b.x = (short)f2bf(xv[c].x); b.y = (short)f2bf(xv[c].y);
        b.z = (short)f2bf(xv[c].z); b.w = (short)f2bf(xv[c].w);
        xbo[lane + 64 * c] = b;
    }

    float acc[NE];
#pragma unroll
    for (int e = 0; e < NE; ++e) {
        const f32x4* wr = (const f32x4*)(Wg + e * DK);
        float a = 0.f;
#pragma unroll
        for (int c = 0; c < 4; ++c) {
            f32x4 wv = wr[lane + 64 * c];
            a += xv[c].x * wv.x + xv[c].y * wv.y + xv[c].z * wv.z + xv[c].w * wv.w;
        }
        acc[e] = a;
    }
#pragma unroll
    for (int e = 0; e < NE; ++e) {
        float a = acc[e];
#pragma unroll
        for (int off = 32; off > 0; off >>= 1) a += __shfl_xor(a, off, 64);
        acc[e] = a;
    }
    if (lane == 0) {
        float v[NE];
#pragma unroll
        for (int e = 0; e < NE; ++e) v[e] = acc[e] + bg[e];
        int b0 = 0; float m0 = v[0];
#pragma unroll
        for (int e = 1; e < NE; ++e) if (v[e] > m0) { m0 = v[e]; b0 = e; }
        int b1 = -1; float m1 = -3.4e38f;
#pragma unroll
        for (int e = 0; e < NE; ++e) if (e != b0 && v[e] > m1) { m1 = v[e]; b1 = e; }
        float r = expf(m1 - m0);
        float s = 1.f + r;
        meta_e[2 * t] = b0; meta_e[2 * t + 1] = b1;
        meta_w[2 * t] = 1.f / s; meta_w[2 * t + 1] = r / s;
    }
}

// ---------------- W -> bf16 ---------------------------------------------------
__global__ __launch_bounds__(256) void k_convw(const float* __restrict__ W,
                                               unsigned short* __restrict__ Wb)
{
    int i = blockIdx.x * 256 + threadIdx.x;
    f32x4 v = ((const f32x4*)W)[i];
    short4v b;
    b.x = (short)f2bf(v.x); b.y = (short)f2bf(v.y);
    b.z = (short)f2bf(v.z); b.w = (short)f2bf(v.w);
    ((short4v*)Wb)[i] = b;
}

// ---------------- per-block histogram (LDS atomics only) ---------------------
__global__ __launch_bounds__(256) void k_hist(const int* __restrict__ meta_e,
                                              int* __restrict__ blockcnt)
{
    __shared__ int lh[NE];
    if (threadIdx.x < NE) lh[threadIdx.x] = 0;
    __syncthreads();
    int base = blockIdx.x * EPB;
#pragma unroll
    for (int k = 0; k < EPB / 256; ++k)
        atomicAdd(&lh[meta_e[base + k * 256 + threadIdx.x]], 1);
    __syncthreads();
    if (threadIdx.x < NE) blockcnt[blockIdx.x * NE + threadIdx.x] = lh[threadIdx.x];
}

// ---------------- scan: expert segs + per-block bases ------------------------
__global__ void k_scan(const int* __restrict__ blockcnt, int* __restrict__ seg,
                       int* __restrict__ base)
{
    __shared__ int pre[HB][NE];
    __shared__ int colsum[NE];
    __shared__ int segstart[NE];
    int tid = threadIdx.x;
    if (tid < NE) {
        int run = 0;
        for (int b = 0; b < HB; ++b) { pre[b][tid] = run; run += blockcnt[b * NE + tid]; }
        colsum[tid] = run;
    }
    __syncthreads();
    if (tid == 0) {
        int s = 0;
        for (int e = 0; e < NE; ++e) { segstart[e] = s; seg[e] = s; s += colsum[e]; }
        seg[NE] = s;
    }
    __syncthreads();
    for (int i = tid; i < HB * NE; i += 64) {
        int b = i / NE, e = i % NE;
        base[i] = segstart[e] + pre[b][e];
    }
}

// ---------------- scatter: ridx[p] = 2t+k (orig slot), rw[p] = weight --------
__global__ __launch_bounds__(256) void k_scatter(const int* __restrict__ meta_e,
    const float* __restrict__ meta_w, const int* __restrict__ base,
    int* __restrict__ ridx, float* __restrict__ rw)
{
    __shared__ int lh[NE];
    __shared__ int bb[NE];
    if (threadIdx.x < NE) {
        lh[threadIdx.x] = 0;
        bb[threadIdx.x] = base[blockIdx.x * NE + threadIdx.x];
    }
    __syncthreads();
    int bs = blockIdx.x * EPB;
#pragma unroll
    for (int k = 0; k < EPB / 256; ++k) {
        int i = bs + k * 256 + threadIdx.x;
        int e = meta_e[i];
        int r = atomicAdd(&lh[e], 1);
        int p = bb[e] + r;
        ridx[p] = i;
        rw[p] = meta_w[i];
    }
}

// ---------------- grouped GEMM, 2-phase pipelined (T3 minimum recipe) --------
// MODE 0: fp32 atomicAdd into out.  MODE 1: bf16 stores to yw.  MODE 2: f32 yw.
template <int MODE>
__global__ __launch_bounds__(256) void k_gemm(const unsigned short* __restrict__ xb,
    const unsigned short* __restrict__ Wb, const float* __restrict__ be,
    const int* __restrict__ seg, const int* __restrict__ ridx,
    const float* __restrict__ rw, float* __restrict__ out, void* __restrict__ ywv)
{
    __shared__ unsigned short Al[2][BM * BK];
    __shared__ unsigned short Bl[2][BN * BK];

    const int e = blockIdx.z;
    const int s0 = seg[e];
    const int L = seg[e + 1] - s0;
    const int m0 = blockIdx.y * BM;
    if (m0 >= L) return;
    const int n0 = blockIdx.x * BN;

    const int tid = threadIdx.x;
    const int lane = tid & 63;
    const int wid = tid >> 6;
    const int wm = wid >> 1, wn = wid & 1;

    const int arow = tid >> 3;
    const int acb = tid & 7;
    const unsigned short* asrc[4];
    const unsigned short* bsrc[4];
#pragma unroll
    for (int c = 0; c < 4; ++c) {
        int r = c * 32 + arow;
        int cbs = acb ^ (r & 7);            // T2 swizzle via pre-swizzled source
        int idx = m0 + r; if (idx >= L) idx = L - 1;
        asrc[c] = xb + (size_t)(ridx[s0 + idx] >> 1) * DK + cbs * 8;
        bsrc[c] = Wb + ((size_t)e * FN + n0 + r) * DK + cbs * 8;
    }

    char* AlB = (char*)&Al[0][0];
    char* BlB = (char*)&Bl[0][0];

    f32x4 acc[4][4];
#pragma unroll
    for (int i = 0; i < 4; ++i)
#pragma unroll
        for (int j = 0; j < 4; ++j) acc[i][j] = f32x4{0.f, 0.f, 0.f, 0.f};

    const int frow = lane & 15;
    const int fq = lane >> 4;
    int a_off[4][2], b_off[4][2];
#pragma unroll
    for (int mi = 0; mi < 4; ++mi) {
        int row = wm * 64 + mi * 16 + frow;
#pragma unroll
        for (int kk = 0; kk < 2; ++kk) {
            int cb = (kk * 4 + fq) ^ (row & 7);
            a_off[mi][kk] = row * 128 + cb * 16;
        }
    }
#pragma unroll
    for (int ni = 0; ni < 4; ++ni) {
        int row = wn * 64 + ni * 16 + frow;
#pragma unroll
        for (int kk = 0; kk < 2; ++kk) {
            int cb = (kk * 4 + fq) ^ (row & 7);
            b_off[ni][kk] = row * 128 + cb * 16;
        }
    }

    auto STAGE = [&](int buf, int kt) {
        const int ko = kt * BK;
#pragma unroll
        for (int c = 0; c < 4; ++c)
            __builtin_amdgcn_global_load_lds(
                (const __attribute__((address_space(1))) void*)(asrc[c] + ko),
                (__attribute__((address_space(3))) void*)(AlB + buf * 16384 + c * 4096 + wid * 1024),
                16, 0, 0);
#pragma unroll
        for (int c = 0; c < 4; ++c)
            __builtin_amdgcn_global_load_lds(
                (const __attribute__((address_space(1))) void*)(bsrc[c] + ko),
                (__attribute__((address_space(3))) void*)(BlB + buf * 16384 + c * 4096 + wid * 1024),
                16, 0, 0);
    };

    auto COMPUTE = [&](int buf) {
        const char* Ab = AlB + buf * 16384;
        const char* Bb = BlB + buf * 16384;
#pragma unroll
        for (int kk = 0; kk < 2; ++kk) {
            short8 af[4], bfr[4];
#pragma unroll
            for (int mi = 0; mi < 4; ++mi) af[mi] = *(const short8*)(Ab + a_off[mi][kk]);
#pragma unroll
            for (int ni = 0; ni < 4; ++ni) bfr[ni] = *(const short8*)(Bb + b_off[ni][kk]);
#pragma unroll
            for (int mi = 0; mi < 4; ++mi)
#pragma unroll
                for (int ni = 0; ni < 4; ++ni)
                    acc[mi][ni] = __builtin_amdgcn_mfma_f32_16x16x32_bf16(
                        af[mi], bfr[ni], acc[mi][ni], 0, 0, 0);
        }
    };

    // prologue
    STAGE(0, 0);
    asm volatile("s_waitcnt vmcnt(0)" ::: "memory");
    __builtin_amdgcn_s_barrier();
    __builtin_amdgcn_sched_barrier(0);

    for (int kt = 0; kt < NIT - 1; ++kt) {
        const int cur = kt & 1;
        STAGE(cur ^ 1, kt + 1);     // next tile in flight under current compute
        COMPUTE(cur);
        asm volatile("s_waitcnt vmcnt(0)" ::: "memory");
        __builtin_amdgcn_s_barrier();
        __builtin_amdgcn_sched_barrier(0);
    }
    COMPUTE((NIT - 1) & 1);

    // epilogue: D col = lane&15, row = (lane>>4)*4 + j
    float bias_n[4];
#pragma unroll
    for (int ni = 0; ni < 4; ++ni)
        bias_n[ni] = be[e * FN + n0 + wn * 64 + ni * 16 + frow];

    const int fq4 = fq * 4;
#pragma unroll
    for (int mi = 0; mi < 4; ++mi) {
        int rl = m0 + wm * 64 + mi * 16 + fq4;
#pragma unroll
        for (int j = 0; j < 4; ++j) {
            int idx = rl + j;
            if (idx < L) {
                float w = rw[s0 + idx];
                int oi = ridx[s0 + idx];
                if (MODE == 0) {
                    float* orow = out + (size_t)(oi >> 1) * FN + n0 + wn * 64 + frow;
#pragma unroll
                    for (int ni = 0; ni < 4; ++ni)
                        atomicAdd(orow + ni * 16, w * (acc[mi][ni][j] + bias_n[ni]));
                } else if (MODE == 1) {
                    unsigned short* yrow = (unsigned short*)ywv + (size_t)oi * FN + n0 + wn * 64 + frow;
#pragma unroll
                    for (int ni = 0; ni < 4; ++ni)
                        yrow[ni * 16] = f2bf(w * (acc[mi][ni][j] + bias_n[ni]));
                } else {
                    float* yrow = (float*)ywv + (size_t)oi * FN + n0 + wn * 64 + frow;
#pragma unroll
                    for (int ni = 0; ni < 4; ++ni)
                        yrow[ni * 16] = w * (acc[mi][ni][j] + bias_n[ni]);
                }
            }
        }
    }
}

// ---------------- combine: out[t] = yw[2t] + yw[2t+1] ------------------------
__global__ __launch_bounds__(256) void k_combine_bf(const unsigned short* __restrict__ yw,
                                                    float* __restrict__ out)
{
    int t = blockIdx.x;
    const short4v* r0 = (const short4v*)(yw + (size_t)(2 * t) * FN);
    const short4v* r1 = (const short4v*)(yw + (size_t)(2 * t + 1) * FN);
    f32x4* o = (f32x4*)(out + (size_t)t * FN);
    int i = threadIdx.x;
    short4v a = r0[i], b = r1[i];
    f32x4 v;
    v.x = bf2f((unsigned short)a.x) + bf2f((unsigned short)b.x);
    v.y = bf2f((unsigned short)a.y) + bf2f((unsigned short)b.y);
    v.z = bf2f((unsigned short)a.z) + bf2f((unsigned short)b.z);
    v.w = bf2f((unsigned short)a.w) + bf2f((unsigned short)b.w);
    o[i] = v;
}

__global__ __launch_bounds__(256) void k_combine_f32(const float* __restrict__ yw,
                                                     float* __restrict__ out)
{
    int t = blockIdx.x;
    const f32x4* r0 = (const f32x4*)(yw + (size_t)(2 * t) * FN);
    const f32x4* r1 = (const f32x4*)(yw + (size_t)(2 * t + 1) * FN);
    f32x4* o = (f32x4*)(out + (size_t)t * FN);
    int i = threadIdx.x;
    o[i] = r0[i] + r1[i];
}

extern "C" void kernel_launch(void* const* d_in, const int* in_sizes, int n_in,
                              void* d_out, int out_size, void* d_ws, size_t ws_size,
                              hipStream_t stream)
{
    const float* x   = (const float*)d_in[0];
    const float* We  = (const float*)d_in[1];
    const float* beb = (const float*)d_in[2];
    const float* Wg  = (const float*)d_in[3];
    const float* bg  = (const float*)d_in[4];
    float* out = (float*)d_out;

    char* ws = (char*)d_ws;
    unsigned short* xb = (unsigned short*)ws;                        // 16 MB
    unsigned short* Wb = (unsigned short*)(ws + (size_t)(16 << 20)); // 16 MB
    size_t off = (size_t)(32 << 20);
    int*   seg      = (int*)(ws + off);   off += 256;
    int*   blockcnt = (int*)(ws + off);   off += HB * NE * 4;
    int*   basebuf  = (int*)(ws + off);   off += HB * NE * 4;
    int*   meta_e   = (int*)(ws + off);   off += (size_t)NTOK * 2 * 4;
    float* meta_w   = (float*)(ws + off); off += (size_t)NTOK * 2 * 4;
    int*   ridxb    = (int*)(ws + off);   off += (size_t)NTOK * 2 * 4;
    float* rwb      = (float*)(ws + off); off += (size_t)NTOK * 2 * 4;
    void*  yw       = (void*)(ws + ((off + 255) & ~(size_t)255));
    size_t yw_base  = (size_t)((off + 255) & ~(size_t)255);

    // pick epilogue mode from available scratch (host-side, deterministic)
    int mode;
    if (ws_size >= yw_base + (size_t)NTOK * 2 * FN * 4) mode = 2;       // f32 yw (64 MB)
    else if (ws_size >= yw_base + (size_t)NTOK * 2 * FN * 2) mode = 1;  // bf16 yw (32 MB)
    else mode = 0;                                                       // atomic fallback

    k_gate<<<NTOK / 4, 256, 0, stream>>>(x, Wg, bg, xb, meta_e, meta_w);
    k_convw<<<(NE * FN * DK / 4) / 256, 256, 0, stream>>>(We, Wb);
    k_hist<<<HB, 256, 0, stream>>>(meta_e, blockcnt);
    k_scan<<<1, 64, 0, stream>>>(blockcnt, seg, basebuf);
    k_scatter<<<HB, 256, 0, stream>>>(meta_e, meta_w, basebuf, ridxb, rwb);

    dim3 g(FN / BN, 64, NE);
    if (mode == 2) {
        k_gemm<2><<<g, 256, 0, stream>>>(xb, Wb, beb, seg, ridxb, rwb, out, yw);
        k_combine_f32<<<NTOK, 256, 0, stream>>>((const float*)yw, out);
    } else if (mode == 1) {
        k_gemm<1><<<g, 256, 0, stream>>>(xb, Wb, beb, seg, ridxb, rwb, out, yw);
        k_combine_bf<<<NTOK, 256, 0, stream>>>((const unsigned short*)yw, out);
    } else {
        hipMemsetAsync(d_out, 0, (size_t)NTOK * FN * 4, stream);
        k_gemm<0><<<g, 256, 0, stream>>>(xb, Wb, beb, seg, ridxb, rwb, out, yw);
    }
}

// Round 4
// 112.547 us; speedup vs baseline: 3.6970x; 1.1831x over previous
//
#include <hip/hip_runtime.h>
#include <hip/hip_bf16.h>
#include <stdint.h>

#define NE 8
#define DK 1024
#define FN 1024
#define NTOK 8192

#define BM 256
#define BN 256
#define BK 64
#define NIT (DK / BK)

#define HB 32
#define EPB (NTOK * 2 / HB)

typedef __attribute__((ext_vector_type(4))) float f32x4;
typedef __attribute__((ext_vector_type(8))) short short8;
typedef __attribute__((ext_vector_type(4))) short short4v;

__device__ __forceinline__ unsigned short f2bf(float f) {
    union { float f; unsigned u; } v; v.f = f;
    unsigned r = v.u;
    unsigned lsb = (r >> 16) & 1u;
    r += 0x7fffu + lsb;
    return (unsigned short)(r >> 16);
}
__device__ __forceinline__ float bf2f(unsigned short u) {
    union { unsigned u; float f; } v; v.u = ((unsigned)u) << 16;
    return v.f;
}

// ---------------- gating + x -> bf16 conversion (one wave per token) ---------
__global__ __launch_bounds__(256) void k_gate(const float* __restrict__ x,
    const float* __restrict__ Wg, const float* __restrict__ bg,
    unsigned short* __restrict__ xb, int* __restrict__ meta_e,
    float* __restrict__ meta_w)
{
    const int lane = threadIdx.x & 63;
    const int t = blockIdx.x * 4 + (threadIdx.x >> 6);

    const f32x4* xr = (const f32x4*)(x + (size_t)t * DK);
    f32x4 xv[4];
#pragma unroll
    for (int c = 0; c < 4; ++c) xv[c] = xr[lane + 64 * c];

    short4v* xbo = (short4v*)(xb + (size_t)t * DK);
#pragma unroll
    for (int c = 0; c < 4; ++c) {
        short4v b;
        b.x = (short)f2bf(xv[c].x); b.y = (short)f2bf(xv[c].y);
        b.z = (short)f2bf(xv[c].z); b.w = (short)f2bf(xv[c].w);
        xbo[lane + 64 * c] = b;
    }

    float acc[NE];
#pragma unroll
    for (int e = 0; e < NE; ++e) {
        const f32x4* wr = (const f32x4*)(Wg + e * DK);
        float a = 0.f;
#pragma unroll
        for (int c = 0; c < 4; ++c) {
            f32x4 wv = wr[lane + 64 * c];
            a += xv[c].x * wv.x + xv[c].y * wv.y + xv[c].z * wv.z + xv[c].w * wv.w;
        }
        acc[e] = a;
    }
#pragma unroll
    for (int e = 0; e < NE; ++e) {
        float a = acc[e];
#pragma unroll
        for (int off = 32; off > 0; off >>= 1) a += __shfl_xor(a, off, 64);
        acc[e] = a;
    }
    if (lane == 0) {
        float v[NE];
#pragma unroll
        for (int e = 0; e < NE; ++e) v[e] = acc[e] + bg[e];
        int b0 = 0; float m0 = v[0];
#pragma unroll
        for (int e = 1; e < NE; ++e) if (v[e] > m0) { m0 = v[e]; b0 = e; }
        int b1 = -1; float m1 = -3.4e38f;
#pragma unroll
        for (int e = 0; e < NE; ++e) if (e != b0 && v[e] > m1) { m1 = v[e]; b1 = e; }
        float r = expf(m1 - m0);
        float s = 1.f + r;
        meta_e[2 * t] = b0; meta_e[2 * t + 1] = b1;
        meta_w[2 * t] = 1.f / s; meta_w[2 * t + 1] = r / s;
    }
}

// ---------------- W -> bf16 ---------------------------------------------------
__global__ __launch_bounds__(256) void k_convw(const float* __restrict__ W,
                                               unsigned short* __restrict__ Wb)
{
    int i = blockIdx.x * 256 + threadIdx.x;
    f32x4 v = ((const f32x4*)W)[i];
    short4v b;
    b.x = (short)f2bf(v.x); b.y = (short)f2bf(v.y);
    b.z = (short)f2bf(v.z); b.w = (short)f2bf(v.w);
    ((short4v*)Wb)[i] = b;
}

// ---------------- per-block histogram (LDS atomics only) ---------------------
__global__ __launch_bounds__(256) void k_hist(const int* __restrict__ meta_e,
                                              int* __restrict__ blockcnt)
{
    __shared__ int lh[NE];
    if (threadIdx.x < NE) lh[threadIdx.x] = 0;
    __syncthreads();
    int base = blockIdx.x * EPB;
#pragma unroll
    for (int k = 0; k < EPB / 256; ++k)
        atomicAdd(&lh[meta_e[base + k * 256 + threadIdx.x]], 1);
    __syncthreads();
    if (threadIdx.x < NE) blockcnt[blockIdx.x * NE + threadIdx.x] = lh[threadIdx.x];
}

// ---------------- scan: expert segs + per-block bases ------------------------
__global__ void k_scan(const int* __restrict__ blockcnt, int* __restrict__ seg,
                       int* __restrict__ base)
{
    __shared__ int pre[HB][NE];
    __shared__ int colsum[NE];
    __shared__ int segstart[NE];
    int tid = threadIdx.x;
    if (tid < NE) {
        int run = 0;
        for (int b = 0; b < HB; ++b) { pre[b][tid] = run; run += blockcnt[b * NE + tid]; }
        colsum[tid] = run;
    }
    __syncthreads();
    if (tid == 0) {
        int s = 0;
        for (int e = 0; e < NE; ++e) { segstart[e] = s; seg[e] = s; s += colsum[e]; }
        seg[NE] = s;
    }
    __syncthreads();
    for (int i = tid; i < HB * NE; i += 64) {
        int b = i / NE, e = i % NE;
        base[i] = segstart[e] + pre[b][e];
    }
}

// ---------------- scatter: ridx[p] = 2t+k (orig slot), rw[p] = weight --------
__global__ __launch_bounds__(256) void k_scatter(const int* __restrict__ meta_e,
    const float* __restrict__ meta_w, const int* __restrict__ base,
    int* __restrict__ ridx, float* __restrict__ rw)
{
    __shared__ int lh[NE];
    __shared__ int bb[NE];
    if (threadIdx.x < NE) {
        lh[threadIdx.x] = 0;
        bb[threadIdx.x] = base[blockIdx.x * NE + threadIdx.x];
    }
    __syncthreads();
    int bs = blockIdx.x * EPB;
#pragma unroll
    for (int k = 0; k < EPB / 256; ++k) {
        int i = bs + k * 256 + threadIdx.x;
        int e = meta_e[i];
        int r = atomicAdd(&lh[e], 1);
        int p = bb[e] + r;
        ridx[p] = i;
        rw[p] = meta_w[i];
    }
}

// ---------------- grouped GEMM, 256x256 2-phase pipeline ---------------------
// 8 waves (2M x 4N), per-wave 128x64 output, LDS 128KB (2 dbuf x (A 32K + B 32K)).
// MODE 0: fp32 atomicAdd into out.  MODE 1: bf16 stores to yw.  MODE 2: f32 yw.
template <int MODE>
__global__ __launch_bounds__(512, 2) void k_gemm(const unsigned short* __restrict__ xb,
    const unsigned short* __restrict__ Wb, const float* __restrict__ be,
    const int* __restrict__ seg, const int* __restrict__ ridx,
    const float* __restrict__ rw, float* __restrict__ out, void* __restrict__ ywv)
{
    __shared__ unsigned short Lds[2 * 2 * BM * BK];   // 128 KB

    const int e = blockIdx.z;
    const int s0 = seg[e];
    const int L = seg[e + 1] - s0;
    const int m0 = blockIdx.y * BM;
    if (m0 >= L) return;
    const int n0 = blockIdx.x * BN;

    const int tid = threadIdx.x;
    const int lane = tid & 63;
    const int wid = tid >> 6;
    const int wm = wid >> 2, wn = wid & 3;   // 2 x 4 wave grid

    // staging: call c covers rows c*64 + tid/8, col-block tid%8 (16B units)
    const int srow = tid >> 3;
    const int scb = tid & 7;
    const unsigned short* asrc[4];
    const unsigned short* bsrc[4];
#pragma unroll
    for (int c = 0; c < 4; ++c) {
        int r = c * 64 + srow;
        int cbs = scb ^ (r & 7);            // swizzle via pre-swizzled source
        int idx = m0 + r; if (idx >= L) idx = L - 1;
        asrc[c] = xb + (size_t)(ridx[s0 + idx] >> 1) * DK + cbs * 8;
        bsrc[c] = Wb + ((size_t)e * FN + n0 + r) * DK + cbs * 8;
    }

    char* LB = (char*)Lds;                   // buf stride 65536; B at +32768

    f32x4 acc[8][4];
#pragma unroll
    for (int i = 0; i < 8; ++i)
#pragma unroll
        for (int j = 0; j < 4; ++j) acc[i][j] = f32x4{0.f, 0.f, 0.f, 0.f};

    const int frow = lane & 15;
    const int fq = lane >> 4;
    int a_off[8][2], b_off[4][2];
#pragma unroll
    for (int mi = 0; mi < 8; ++mi) {
        int row = wm * 128 + mi * 16 + frow;
#pragma unroll
        for (int kk = 0; kk < 2; ++kk) {
            int cb = (kk * 4 + fq) ^ (row & 7);
            a_off[mi][kk] = row * 128 + cb * 16;
        }
    }
#pragma unroll
    for (int ni = 0; ni < 4; ++ni) {
        int row = wn * 64 + ni * 16 + frow;
#pragma unroll
        for (int kk = 0; kk < 2; ++kk) {
            int cb = (kk * 4 + fq) ^ (row & 7);
            b_off[ni][kk] = 32768 + row * 128 + cb * 16;
        }
    }

    auto STAGE = [&](int buf, int kt) {
        const int ko = kt * BK;
        char* dstA = LB + buf * 65536 + wid * 1024;
        char* dstB = dstA + 32768;
#pragma unroll
        for (int c = 0; c < 4; ++c)
            __builtin_amdgcn_global_load_lds(
                (const __attribute__((address_space(1))) void*)(asrc[c] + ko),
                (__attribute__((address_space(3))) void*)(dstA + c * 8192),
                16, 0, 0);
#pragma unroll
        for (int c = 0; c < 4; ++c)
            __builtin_amdgcn_global_load_lds(
                (const __attribute__((address_space(1))) void*)(bsrc[c] + ko),
                (__attribute__((address_space(3))) void*)(dstB + c * 8192),
                16, 0, 0);
    };

    auto COMPUTE = [&](int buf) {
        const char* base = LB + buf * 65536;
#pragma unroll
        for (int kk = 0; kk < 2; ++kk) {
            short8 af[8], bfr[4];
#pragma unroll
            for (int mi = 0; mi < 8; ++mi) af[mi] = *(const short8*)(base + a_off[mi][kk]);
#pragma unroll
            for (int ni = 0; ni < 4; ++ni) bfr[ni] = *(const short8*)(base + b_off[ni][kk]);
#pragma unroll
            for (int mi = 0; mi < 8; ++mi)
#pragma unroll
                for (int ni = 0; ni < 4; ++ni)
                    acc[mi][ni] = __builtin_amdgcn_mfma_f32_16x16x32_bf16(
                        af[mi], bfr[ni], acc[mi][ni], 0, 0, 0);
        }
    };

    // prologue
    STAGE(0, 0);
    asm volatile("s_waitcnt vmcnt(0)" ::: "memory");
    __builtin_amdgcn_s_barrier();
    __builtin_amdgcn_sched_barrier(0);

    for (int kt = 0; kt < NIT - 1; ++kt) {
        const int cur = kt & 1;
        STAGE(cur ^ 1, kt + 1);     // next tile in flight under current compute
        COMPUTE(cur);
        asm volatile("s_waitcnt vmcnt(0)" ::: "memory");
        __builtin_amdgcn_s_barrier();
        __builtin_amdgcn_sched_barrier(0);
    }
    COMPUTE((NIT - 1) & 1);

    // epilogue: D col = lane&15, row = (lane>>4)*4 + j
    float bias_n[4];
#pragma unroll
    for (int ni = 0; ni < 4; ++ni)
        bias_n[ni] = be[e * FN + n0 + wn * 64 + ni * 16 + frow];

    const int fq4 = fq * 4;
#pragma unroll
    for (int mi = 0; mi < 8; ++mi) {
        int rl = m0 + wm * 128 + mi * 16 + fq4;
#pragma unroll
        for (int j = 0; j < 4; ++j) {
            int idx = rl + j;
            if (idx < L) {
                float w = rw[s0 + idx];
                int oi = ridx[s0 + idx];
                if (MODE == 0) {
                    float* orow = out + (size_t)(oi >> 1) * FN + n0 + wn * 64 + frow;
#pragma unroll
                    for (int ni = 0; ni < 4; ++ni)
                        atomicAdd(orow + ni * 16, w * (acc[mi][ni][j] + bias_n[ni]));
                } else if (MODE == 1) {
                    unsigned short* yrow = (unsigned short*)ywv + (size_t)oi * FN + n0 + wn * 64 + frow;
#pragma unroll
                    for (int ni = 0; ni < 4; ++ni)
                        yrow[ni * 16] = f2bf(w * (acc[mi][ni][j] + bias_n[ni]));
                } else {
                    float* yrow = (float*)ywv + (size_t)oi * FN + n0 + wn * 64 + frow;
#pragma unroll
                    for (int ni = 0; ni < 4; ++ni)
                        yrow[ni * 16] = w * (acc[mi][ni][j] + bias_n[ni]);
                }
            }
        }
    }
}

// ---------------- combine: out[t] = yw[2t] + yw[2t+1] ------------------------
__global__ __launch_bounds__(256) void k_combine_bf(const unsigned short* __restrict__ yw,
                                                    float* __restrict__ out)
{
    int t = blockIdx.x;
    const short4v* r0 = (const short4v*)(yw + (size_t)(2 * t) * FN);
    const short4v* r1 = (const short4v*)(yw + (size_t)(2 * t + 1) * FN);
    f32x4* o = (f32x4*)(out + (size_t)t * FN);
    int i = threadIdx.x;
    short4v a = r0[i], b = r1[i];
    f32x4 v;
    v.x = bf2f((unsigned short)a.x) + bf2f((unsigned short)b.x);
    v.y = bf2f((unsigned short)a.y) + bf2f((unsigned short)b.y);
    v.z = bf2f((unsigned short)a.z) + bf2f((unsigned short)b.z);
    v.w = bf2f((unsigned short)a.w) + bf2f((unsigned short)b.w);
    o[i] = v;
}

__global__ __launch_bounds__(256) void k_combine_f32(const float* __restrict__ yw,
                                                     float* __restrict__ out)
{
    int t = blockIdx.x;
    const f32x4* r0 = (const f32x4*)(yw + (size_t)(2 * t) * FN);
    const f32x4* r1 = (const f32x4*)(yw + (size_t)(2 * t + 1) * FN);
    f32x4* o = (f32x4*)(out + (size_t)t * FN);
    int i = threadIdx.x;
    o[i] = r0[i] + r1[i];
}

extern "C" void kernel_launch(void* const* d_in, const int* in_sizes, int n_in,
                              void* d_out, int out_size, void* d_ws, size_t ws_size,
                              hipStream_t stream)
{
    const float* x   = (const float*)d_in[0];
    const float* We  = (const float*)d_in[1];
    const float* beb = (const float*)d_in[2];
    const float* Wg  = (const float*)d_in[3];
    const float* bg  = (const float*)d_in[4];
    float* out = (float*)d_out;

    char* ws = (char*)d_ws;
    unsigned short* xb = (unsigned short*)ws;                        // 16 MB
    unsigned short* Wb = (unsigned short*)(ws + (size_t)(16 << 20)); // 16 MB
    size_t off = (size_t)(32 << 20);
    int*   seg      = (int*)(ws + off);   off += 256;
    int*   blockcnt = (int*)(ws + off);   off += HB * NE * 4;
    int*   basebuf  = (int*)(ws + off);   off += HB * NE * 4;
    int*   meta_e   = (int*)(ws + off);   off += (size_t)NTOK * 2 * 4;
    float* meta_w   = (float*)(ws + off); off += (size_t)NTOK * 2 * 4;
    int*   ridxb    = (int*)(ws + off);   off += (size_t)NTOK * 2 * 4;
    float* rwb      = (float*)(ws + off); off += (size_t)NTOK * 2 * 4;
    void*  yw       = (void*)(ws + ((off + 255) & ~(size_t)255));
    size_t yw_base  = (size_t)((off + 255) & ~(size_t)255);

    // pick epilogue mode from available scratch (host-side, deterministic).
    // prefer bf16 yw: halves epilogue-write + combine-read traffic.
    int mode;
    if (ws_size >= yw_base + (size_t)NTOK * 2 * FN * 2) mode = 1;       // bf16 yw (32 MB)
    else if (ws_size >= yw_base + (size_t)NTOK * 2 * FN * 4) mode = 2;  // f32 yw (64 MB)
    else mode = 0;                                                      // atomic fallback

    k_gate<<<NTOK / 4, 256, 0, stream>>>(x, Wg, bg, xb, meta_e, meta_w);
    k_convw<<<(NE * FN * DK / 4) / 256, 256, 0, stream>>>(We, Wb);
    k_hist<<<HB, 256, 0, stream>>>(meta_e, blockcnt);
    k_scan<<<1, 64, 0, stream>>>(blockcnt, seg, basebuf);
    k_scatter<<<HB, 256, 0, stream>>>(meta_e, meta_w, basebuf, ridxb, rwb);

    dim3 g(FN / BN, 32, NE);
    if (mode == 1) {
        k_gemm<1><<<g, 512, 0, stream>>>(xb, Wb, beb, seg, ridxb, rwb, out, yw);
        k_combine_bf<<<NTOK, 256, 0, stream>>>((const unsigned short*)yw, out);
    } else if (mode == 2) {
        k_gemm<2><<<g, 512, 0, stream>>>(xb, Wb, beb, seg, ridxb, rwb, out, yw);
        k_combine_f32<<<NTOK, 256, 0, stream>>>((const float*)yw, out);
    } else {
        hipMemsetAsync(d_out, 0, (size_t)NTOK * FN * 4, stream);
        k_gemm<0><<<g, 512, 0, stream>>>(xb, Wb, beb, seg, ridxb, rwb, out, yw);
    }
}